// Round 7
// baseline (48.221 us; speedup 1.0000x reference)
//
#include <hip/hip_runtime.h>
#include <hip/hip_bf16.h>

#define BATCH 64
#define HH 32
#define WW 32
#define CIN 64
#define COUT 64
#define KFEAT 576   // 3*3*64, flattened as ci*9 + kh*3 + kw (ci major)

typedef __bf16 bf16x8 __attribute__((ext_vector_type(8)));
typedef float f32x16 __attribute__((ext_vector_type(16)));

static __device__ __forceinline__ ushort f2bf_bits(float f) {
  __bf16 b = (__bf16)f;
  return __builtin_bit_cast(ushort, b);
}

// One block per output pixel (h,w). 256 threads = 4 waves.
// Per-pixel GEMM: C[64b][64co] += patches[64b][64ci] * K[ci][co] per pixel p,
// phase-aligned order (R5). ROUND-7 DELTA: 32x32x16 MFMA with waves split
// along k (wave w owns ci 16w..16w+15, partials reduced once via LDS at end).
// Why: 32-wide B-fragment makes every weight load instruction request TWO
// FULL 128-B L2 lines (vs 4 half-lines with 16x16) -- the weight stream is
// 78% of traffic and was flowing as 64-B granules. Epilogue also moves to
// 256-B contiguous float4 writes via an LDS C-buffer.
__global__ __launch_bounds__(256, 4) void LocalConv_kernel(
    const float* __restrict__ in, const float* __restrict__ ker,
    const float* __restrict__ bias, float* __restrict__ out) {
  // A buffers: [2][64 rows][64 ci] bf16, row stride 128B, XOR-swizzled by
  // byte ^= ((row&7)<<4) (G4). Reused as the f32 C-buffer (16KB) at the end.
  __shared__ __align__(16) ushort Ab[2][64 * 64];

  const int orig = blockIdx.x;
  // XCD-aware swizzle (T1): 128 contiguous blocks per XCD.
  const int hw = (orig & 7) * 128 + (orig >> 3);
  const int h = hw >> 5, w = hw & 31;
  const int hm = h % 3, wm = w % 3;
  const int tid = threadIdx.x;
  const int lane = tid & 63;
  const int wave = tid >> 6;

  const float* kerhw = ker + (size_t)hw * (KFEAT * COUT);

  // Step t -> (hp, wp, p): the unique 3x3-neighbor with hp===t/3, wp===t%3
  // (mod 3) -- all 9 readers of an input tile touch it at the same step.
  auto offs = [&](int t, int& hp, int& wp, int& p) {
    const int t3 = t / 3, t0 = t % 3;
    const int dh = ((t3 + 4 - hm) % 3) - 1;
    const int dw = ((t0 + 4 - wm) % 3) - 1;
    hp = h + dh;
    wp = w + dw;
    p = (dh + 1) * 3 + (dw + 1);
  };

  float4 st[4];  // in-flight staging regs (issue-early / write-late)

  auto issue_step = [&](int t) {
    int hp, wp, pu;
    offs(t, hp, wp, pu);
    const bool ok = ((unsigned)hp < (unsigned)HH) && ((unsigned)wp < (unsigned)WW);
    const float* src = in + ((size_t)hp * WW + wp) * CIN;
#pragma unroll
    for (int i = 0; i < 4; ++i) {
      const int c = i * 256 + tid;       // 0..1023 chunks of float4
      const int brow = c >> 4;           // batch row 0..63
      const int c16 = c & 15;            // float4 index within row
      if (ok) {
        st[i] = *reinterpret_cast<const float4*>(
            src + (size_t)brow * (HH * WW * CIN) + c16 * 4);
      } else {
        st[i] = make_float4(0.f, 0.f, 0.f, 0.f);  // SAME zero padding
      }
    }
  };

  auto writebuf = [&](int buf_idx) {
    ushort* buf = &Ab[buf_idx][0];
#pragma unroll
    for (int i = 0; i < 4; ++i) {
      const int c = i * 256 + tid;
      const int brow = c >> 4, c16 = c & 15;
      union { ushort us[4]; uint2 u2; } pk;
      pk.us[0] = f2bf_bits(st[i].x);
      pk.us[1] = f2bf_bits(st[i].y);
      pk.us[2] = f2bf_bits(st[i].z);
      pk.us[3] = f2bf_bits(st[i].w);
      const int byteofs = brow * 128 + ((c16 * 8) ^ ((brow & 7) << 4));
      *reinterpret_cast<uint2*>(reinterpret_cast<char*>(buf) + byteofs) = pk.u2;
    }
  };

  // Wave w owns ci slice [16w, 16w+16). Fragment slot (lane>>5, j) carries
  // ci = 16w + (lane>>5)*8 + j in BOTH A and B, so the MFMA k-pairing is
  // consistent whatever the hardware's internal k permutation.
  const int l31 = lane & 31;
  const int khalf = lane >> 5;  // 0 or 1
  const int ci_lo = wave * 16 + khalf * 8;  // first of 8 consecutive ci

  f32x16 acc[2][2];  // [mt][nt], 32x32 tile each; 64 VGPRs
#pragma unroll
  for (int mt = 0; mt < 2; ++mt)
#pragma unroll
    for (int nt = 0; nt < 2; ++nt)
#pragma unroll
      for (int r = 0; r < 16; ++r) acc[mt][nt][r] = 0.f;

  // Prologue: tile 0 -> LDS, tile 1 loads in flight.
  issue_step(0);
  writebuf(0);
  __syncthreads();

  for (int t = 0; t < 9; ++t) {
    if (t < 8) issue_step(t + 1);

    int hh_, ww_, pcur;
    offs(t, hh_, ww_, pcur);

    // Weight base for this pixel: element (ci, co) at kerhw[ci*576+pcur*64+co]
    const float* kpw = kerhw + pcur * COUT + l31 + (size_t)ci_lo * KFEAT;

    // B-fragments: lanes 0-31 = one 128-B line (co 0..31 contiguous),
    // lanes 32-63 = the line 8 ci-rows later. Two full lines per load.
    bf16x8 bf[2];
#pragma unroll
    for (int nt = 0; nt < 2; ++nt) {
      float wf[8];
#pragma unroll
      for (int j = 0; j < 8; ++j) wf[j] = kpw[(size_t)j * KFEAT + nt * 32];
#pragma unroll
      for (int j = 0; j < 8; ++j) bf[nt][j] = (__bf16)wf[j];
    }

    // A-fragments from LDS: row = mt*32 + l31, 8 contiguous ci at ci_lo.
    const ushort* buf = &Ab[t & 1][0];
#pragma unroll
    for (int mt = 0; mt < 2; ++mt) {
      const int row = mt * 32 + l31;
      const int byteofs = row * 128 + ((ci_lo * 2) ^ ((row & 7) << 4));
      bf16x8 af = *reinterpret_cast<const bf16x8*>(
          reinterpret_cast<const char*>(buf) + byteofs);
#pragma unroll
      for (int nt = 0; nt < 2; ++nt)
        acc[mt][nt] = __builtin_amdgcn_mfma_f32_32x32x16_bf16(
            af, bf[nt], acc[mt][nt], 0, 0, 0);
    }

    __syncthreads();  // all reads of Ab[t&1] done
    if (t < 8) {
      writebuf((t + 1) & 1);
      __syncthreads();  // visible before compute(t+1)
    }
  }

  // Cross-wave k-reduction in LDS (Ab reused as f32 C[64][64], 16 KB).
  // C rows are 256 B; lane bank = co%32 -> conflict-free.
  float* Cbuf = reinterpret_cast<float*>(&Ab[0][0]);
  __syncthreads();  // all LDS reads of Ab done before overwrite
#pragma unroll 1
  for (int r = 0; r < 4; ++r) {
    if (wave == r) {
#pragma unroll
      for (int mt = 0; mt < 2; ++mt)
#pragma unroll
        for (int nt = 0; nt < 2; ++nt)
#pragma unroll
          for (int g = 0; g < 16; ++g) {
            const int row = mt * 32 + (g & 3) + 8 * (g >> 2) + 4 * khalf;
            const int col = nt * 32 + l31;
            if (r == 0)
              Cbuf[row * 64 + col] = acc[mt][nt][g];
            else
              Cbuf[row * 64 + col] += acc[mt][nt][g];
          }
    }
    __syncthreads();
  }

  // Epilogue: bias + 256-B-contiguous float4 stores.
  // Thread t: b rows t>>4 + 16i, co chunk (t&15)*4.
  const int co4 = (tid & 15) * 4;
  const float4 bv4 = *reinterpret_cast<const float4*>(bias + hw * COUT + co4);
#pragma unroll
  for (int i = 0; i < 4; ++i) {
    const int b = (tid >> 4) + i * 16;
    float4 v = *reinterpret_cast<const float4*>(&Cbuf[b * 64 + co4]);
    v.x += bv4.x; v.y += bv4.y; v.z += bv4.z; v.w += bv4.w;
    *reinterpret_cast<float4*>(
        out + ((size_t)b * (HH * WW) + hw) * COUT + co4) = v;
  }
}

extern "C" void kernel_launch(void* const* d_in, const int* in_sizes, int n_in,
                              void* d_out, int out_size, void* d_ws,
                              size_t ws_size, hipStream_t stream) {
  const float* in = (const float*)d_in[0];
  const float* ker = (const float*)d_in[1];
  const float* bias = (const float*)d_in[2];
  float* out = (float*)d_out;
  (void)in_sizes; (void)n_in; (void)out_size; (void)d_ws; (void)ws_size;
  LocalConv_kernel<<<dim3(HH * WW), dim3(256), 0, stream>>>(in, ker, bias, out);
}

// Round 8
// 34.945 us; speedup vs baseline: 1.3799x; 1.3799x over previous
//
#include <hip/hip_runtime.h>
#include <hip/hip_bf16.h>

#define BATCH 64
#define HH 32
#define WW 32
#define CIN 64
#define COUT 64
#define KFEAT 576   // 3*3*64, flattened as ci*9 + kh*3 + kw (ci major)

typedef __bf16 bf16x8 __attribute__((ext_vector_type(8)));
typedef float f32x4 __attribute__((ext_vector_type(4)));

static __device__ __forceinline__ ushort f2bf_bits(float f) {
  __bf16 b = (__bf16)f;
  return __builtin_bit_cast(ushort, b);
}

// ROUND-8: R5 structure, batch SPLIT IN TWO -> 2048 blocks = 8 blocks/CU =
// 32 waves/CU. Little's-law analysis of R5 (16 waves/CU x ~20 outstanding
// 64-B reads x ~900ns = 5.7 TB/s, matching the measured 5.5) says we are
// MEMORY-CONCURRENCY limited, not byte limited (R7 counters: FETCH=86MB,
// everything idle). Doubling resident waves doubles in-flight requests.
// The two blocks sharing one hw (weight tile) sit on the SAME XCD at the
// SAME phase (pair ids 8 apart; phase-aligned loop) -> L2 dedups weights.
// Per block: 32 batch rows, A-tile 4KB bf16 (XOR-swizzled, double-buffered,
// 2 barriers/step), acc 8 VGPR, st 8 VGPR, launch_bounds(256,8) => VGPR<=64.
__global__ __launch_bounds__(256, 8) void LocalConv_kernel(
    const float* __restrict__ in, const float* __restrict__ ker,
    const float* __restrict__ bias, float* __restrict__ out) {
  // A buffers: [2][32 rows][64 ci] bf16, row stride 128B, XOR-swizzled by
  // byte ^= ((row&7)<<4) (G4).
  __shared__ __align__(16) ushort Ab[2][32 * 64];

  const int orig = blockIdx.x;           // 0..2047
  // XCD swizzle (T1): xcd = orig&7 (dispatch round-robin). r>>1 sweeps hw,
  // r&1 is the batch half -> the pair (bh=0,1) of one hw is 8 apart in
  // dispatch order: same XCD, launched back-to-back.
  const int xcd = orig & 7;
  const int r = orig >> 3;               // 0..255
  const int bh = r & 1;                  // batch half: rows bh*32..bh*32+31
  const int hw = xcd * 128 + (r >> 1);   // 0..1023
  const int h = hw >> 5, w = hw & 31;
  const int hm = h % 3, wm = w % 3;
  const int tid = threadIdx.x;
  const int lane = tid & 63;
  const int wave = tid >> 6;

  const float* kerhw = ker + (size_t)hw * (KFEAT * COUT);

  // Step t -> (hp, wp, p): the unique 3x3-neighbor with hp===t/3, wp===t%3
  // (mod 3) -- all readers of an input tile touch it at the same step (R5).
  auto offs = [&](int t, int& hp, int& wp, int& p) {
    const int t3 = t / 3, t0 = t % 3;
    const int dh = ((t3 + 4 - hm) % 3) - 1;
    const int dw = ((t0 + 4 - wm) % 3) - 1;
    hp = h + dh;
    wp = w + dw;
    p = (dh + 1) * 3 + (dw + 1);
  };

  float4 st[2];  // in-flight staging regs (32 rows x 64 ci = 512 float4)

  auto issue_step = [&](int t) {
    int hp, wp, pu;
    offs(t, hp, wp, pu);
    const bool ok = ((unsigned)hp < (unsigned)HH) && ((unsigned)wp < (unsigned)WW);
    const float* src = in + ((size_t)hp * WW + wp) * CIN;
#pragma unroll
    for (int i = 0; i < 2; ++i) {
      const int c = i * 256 + tid;       // 0..511 chunks of float4
      const int brow = c >> 4;           // local batch row 0..31
      const int c16 = c & 15;            // float4 index within row
      if (ok) {
        st[i] = *reinterpret_cast<const float4*>(
            src + (size_t)(bh * 32 + brow) * (HH * WW * CIN) + c16 * 4);
      } else {
        st[i] = make_float4(0.f, 0.f, 0.f, 0.f);  // SAME zero padding
      }
    }
  };

  auto writebuf = [&](int buf_idx) {
    ushort* buf = &Ab[buf_idx][0];
#pragma unroll
    for (int i = 0; i < 2; ++i) {
      const int c = i * 256 + tid;
      const int brow = c >> 4, c16 = c & 15;
      union { ushort us[4]; uint2 u2; } pk;
      pk.us[0] = f2bf_bits(st[i].x);
      pk.us[1] = f2bf_bits(st[i].y);
      pk.us[2] = f2bf_bits(st[i].z);
      pk.us[3] = f2bf_bits(st[i].w);
      const int byteofs = brow * 128 + ((c16 * 8) ^ ((brow & 7) << 4));
      *reinterpret_cast<uint2*>(reinterpret_cast<char*>(buf) + byteofs) = pk.u2;
    }
  };

  f32x4 acc[2];  // two 16-row m-tiles of the 32-row block
#pragma unroll
  for (int m = 0; m < 2; ++m) acc[m] = (f32x4){0.f, 0.f, 0.f, 0.f};

  const int co = wave * 16 + (lane & 15);  // this wave's co slice
  const int kgrp = lane >> 4;              // 0..3, k-group within frag

  issue_step(0);
  writebuf(0);
  __syncthreads();

  for (int t = 0; t < 9; ++t) {
    if (t < 8) issue_step(t + 1);  // HBM latency hides under compute below

    int hh_, ww_, pcur;
    offs(t, hh_, ww_, pcur);

    const ushort* buf = &Ab[t & 1][0];
    // kernel element (ci,co) for pixel pcur: kerhw[ci*576 + pcur*64 + co]
    const float* kp = kerhw + pcur * COUT + co;
#pragma unroll
    for (int ks = 0; ks < 2; ++ks) {  // two K=32 steps per pixel
      const int ci0 = ks * 32 + kgrp * 8;
      bf16x8 bfrag;
#pragma unroll
      for (int j = 0; j < 8; ++j)
        bfrag[j] = (__bf16)kp[(size_t)(ci0 + j) * KFEAT];
#pragma unroll
      for (int m = 0; m < 2; ++m) {
        const int row = m * 16 + (lane & 15);
        const int byteofs =
            row * 128 + ((ks * 64 + kgrp * 16) ^ ((row & 7) << 4));
        bf16x8 afrag = *reinterpret_cast<const bf16x8*>(
            reinterpret_cast<const char*>(buf) + byteofs);
        acc[m] = __builtin_amdgcn_mfma_f32_16x16x32_bf16(afrag, bfrag, acc[m],
                                                         0, 0, 0);
      }
    }

    __syncthreads();  // all reads of Ab[t&1] done
    if (t < 8) {
      writebuf((t + 1) & 1);
      __syncthreads();  // visible before compute(t+1)
    }
  }

  // Epilogue: C/D layout (16x16x32): col = lane&15, row = (lane>>4)*4 + reg.
  const float bv = bias[hw * COUT + co];
#pragma unroll
  for (int m = 0; m < 2; ++m) {
#pragma unroll
    for (int rr = 0; rr < 4; ++rr) {
      const int b = bh * 32 + m * 16 + kgrp * 4 + rr;
      out[((size_t)b * (HH * WW) + hw) * COUT + co] = acc[m][rr] + bv;
    }
  }
}

extern "C" void kernel_launch(void* const* d_in, const int* in_sizes, int n_in,
                              void* d_out, int out_size, void* d_ws,
                              size_t ws_size, hipStream_t stream) {
  const float* in = (const float*)d_in[0];
  const float* ker = (const float*)d_in[1];
  const float* bias = (const float*)d_in[2];
  float* out = (float*)d_out;
  (void)in_sizes; (void)n_in; (void)out_size; (void)d_ws; (void)ws_size;
  LocalConv_kernel<<<dim3(2048), dim3(256), 0, stream>>>(in, ker, bias, out);
}

// Round 9
// 34.851 us; speedup vs baseline: 1.3836x; 1.0027x over previous
//
#include <hip/hip_runtime.h>
#include <hip/hip_bf16.h>

#define HH 32
#define WW 32
#define CIN 64
#define COUT 64
#define KFEAT 576   // 3*3*64, flattened as ci*9 + kh*3 + kw (ci major)

typedef __bf16 bf16x8 __attribute__((ext_vector_type(8)));
typedef float f32x4 __attribute__((ext_vector_type(4)));

static __device__ __forceinline__ ushort f2bf_bits(float f) {
  __bf16 b = (__bf16)f;
  return __builtin_bit_cast(ushort, b);
}

// One block per output pixel (h,w), 256 threads = 4 waves (R5 grid: weights
// read exactly once device-wide). ROUND-9 DELTA: the weight tile is STAGED
// THROUGH LDS like the input tile -- per pixel, 16KB loaded as thread-linear
// float4 (1-KB contiguous bursts per wave-instr, 4x fewer VMEM instrs,
// perfectly ascending addresses) instead of 16 scalar dwords/lane scattered
// over 18KB. B-frags then come from LDS. Epilogue goes LDS-transposed ->
// 256-B-chunk float4 stores. Attacks stream SHAPE (granularity/sequentiality),
// the only unexplored limiter after R3/R6/R8 nulls.
__global__ __launch_bounds__(256, 4) void LocalConv_kernel(
    const float* __restrict__ in, const float* __restrict__ ker,
    const float* __restrict__ bias, float* __restrict__ out) {
  // A: [2][64 b][64 ci] bf16, rows 128B, XOR swz ((row&7)<<4)  (16 KB)
  // B: [2][64 ci][64 co] bf16, rows 128B, XOR swz (((ci>>3)&3)<<5) (16 KB)
  __shared__ __align__(16) ushort Ab[2][64 * 64];
  __shared__ __align__(16) ushort Bb[2][64 * 64];

  const int orig = blockIdx.x;
  // XCD swizzle (T1): 128 contiguous hw per XCD.
  const int hw = (orig & 7) * 128 + (orig >> 3);
  const int h = hw >> 5, w = hw & 31;
  const int hm = h % 3, wm = w % 3;
  const int tid = threadIdx.x;
  const int lane = tid & 63;
  const int wave = tid >> 6;

  const float* kerhw = ker + (size_t)hw * (KFEAT * COUT);

  // Phase-aligned order (R5): step t -> neighbor with hp%3==t/3, wp%3==t%3.
  auto offs = [&](int t, int& hp, int& wp, int& p) {
    const int t3 = t / 3, t0 = t % 3;
    const int dh = ((t3 + 4 - hm) % 3) - 1;
    const int dw = ((t0 + 4 - wm) % 3) - 1;
    hp = h + dh;
    wp = w + dw;
    p = (dh + 1) * 3 + (dw + 1);
  };

  float4 stA[4], stB[4];  // in-flight staging regs (issue-early/write-late)

  auto issueA = [&](int t) {
    int hp, wp, pu;
    offs(t, hp, wp, pu);
    const bool ok = ((unsigned)hp < (unsigned)HH) && ((unsigned)wp < (unsigned)WW);
    const float* src = in + ((size_t)hp * WW + wp) * CIN;
#pragma unroll
    for (int i = 0; i < 4; ++i) {
      const int c = i * 256 + tid;   // 0..1023
      const int brow = c >> 4, c16 = c & 15;
      if (ok) {
        stA[i] = *reinterpret_cast<const float4*>(
            src + (size_t)brow * (HH * WW * CIN) + c16 * 4);
      } else {
        stA[i] = make_float4(0.f, 0.f, 0.f, 0.f);  // SAME zero padding
      }
    }
  };

  auto issueB = [&](int t) {
    int hp, wp, p;
    offs(t, hp, wp, p);
    // element (ci,co) of pixel p at kerhw[ci*576 + p*64 + co]
    const float* src = kerhw + p * COUT;
#pragma unroll
    for (int i = 0; i < 4; ++i) {
      const int c = i * 256 + tid;   // 0..1023
      const int ci = c >> 4, co4 = c & 15;
      stB[i] = *reinterpret_cast<const float4*>(
          src + (size_t)ci * KFEAT + co4 * 4);
    }
  };

  auto writeA = [&](int bi) {
    ushort* buf = &Ab[bi][0];
#pragma unroll
    for (int i = 0; i < 4; ++i) {
      const int c = i * 256 + tid;
      const int brow = c >> 4, c16 = c & 15;
      union { ushort us[4]; uint2 u2; } pk;
      pk.us[0] = f2bf_bits(stA[i].x);
      pk.us[1] = f2bf_bits(stA[i].y);
      pk.us[2] = f2bf_bits(stA[i].z);
      pk.us[3] = f2bf_bits(stA[i].w);
      const int byteofs = brow * 128 + ((c16 * 8) ^ ((brow & 7) << 4));
      *reinterpret_cast<uint2*>(reinterpret_cast<char*>(buf) + byteofs) = pk.u2;
    }
  };

  auto writeB = [&](int bi) {
    ushort* buf = &Bb[bi][0];
#pragma unroll
    for (int i = 0; i < 4; ++i) {
      const int c = i * 256 + tid;
      const int ci = c >> 4, co4 = c & 15;
      union { ushort us[4]; uint2 u2; } pk;
      pk.us[0] = f2bf_bits(stB[i].x);
      pk.us[1] = f2bf_bits(stB[i].y);
      pk.us[2] = f2bf_bits(stB[i].z);
      pk.us[3] = f2bf_bits(stB[i].w);
      const int byteofs = ci * 128 + ((co4 * 8) ^ (((ci >> 3) & 3) << 5));
      *reinterpret_cast<uint2*>(reinterpret_cast<char*>(buf) + byteofs) = pk.u2;
    }
  };

  f32x4 acc[4];
#pragma unroll
  for (int m = 0; m < 4; ++m) acc[m] = (f32x4){0.f, 0.f, 0.f, 0.f};

  const int co = wave * 16 + (lane & 15);  // this wave's co slice
  const int kgrp = lane >> 4;              // 0..3

  issueA(0);
  issueB(0);
  writeA(0);
  writeB(0);
  __syncthreads();

  for (int t = 0; t < 9; ++t) {
    if (t < 8) {
      issueA(t + 1);  // in flight during compute
      issueB(t + 1);
    }

    const ushort* bufA = &Ab[t & 1][0];
    const ushort* bufB = &Bb[t & 1][0];
#pragma unroll
    for (int ks = 0; ks < 2; ++ks) {  // two K=32 steps per pixel
      bf16x8 bfrag;
#pragma unroll
      for (int j = 0; j < 8; ++j) {
        const int ci = ks * 32 + kgrp * 8 + j;
        const int byteofs = ci * 128 + ((co * 2) ^ (((ci >> 3) & 3) << 5));
        bfrag[j] = __builtin_bit_cast(__bf16, *reinterpret_cast<const ushort*>(
            reinterpret_cast<const char*>(bufB) + byteofs));
      }
#pragma unroll
      for (int m = 0; m < 4; ++m) {
        const int row = m * 16 + (lane & 15);
        const int byteofs =
            row * 128 + ((ks * 64 + kgrp * 16) ^ ((row & 7) << 4));
        bf16x8 afrag = *reinterpret_cast<const bf16x8*>(
            reinterpret_cast<const char*>(bufA) + byteofs);
        acc[m] = __builtin_amdgcn_mfma_f32_16x16x32_bf16(afrag, bfrag, acc[m],
                                                         0, 0, 0);
      }
    }

    __syncthreads();  // all LDS reads of buffers t&1 done
    if (t < 8) {
      writeA((t + 1) & 1);
      writeB((t + 1) & 1);
      __syncthreads();  // visible before compute(t+1)
    }
  }

  // Epilogue via LDS transpose (reuse Ab as C[64 b][64 co] f32, 16 KB).
  // The loop's final barrier guarantees all reads of Ab/Bb are done.
  float* C = reinterpret_cast<float*>(&Ab[0][0]);
  const float bv = bias[hw * COUT + co];
#pragma unroll
  for (int m = 0; m < 4; ++m) {
#pragma unroll
    for (int r = 0; r < 4; ++r) {
      const int b = m * 16 + kgrp * 4 + r;
      // XOR 16-element (64B) groups by (b>>2)&3 to spread bank rows.
      C[b * 64 + (co ^ (((b >> 2) & 3) << 4))] = acc[m][r] + bv;
    }
  }
  __syncthreads();

  // 256-B-chunk stores: thread -> (b = tid>>4 + 16i, co quad (tid&15)*4).
  const int co4q = (tid & 15) * 4;
#pragma unroll
  for (int i = 0; i < 4; ++i) {
    const int b = (tid >> 4) + i * 16;
    const float4 v = *reinterpret_cast<const float4*>(
        &C[b * 64 + (co4q ^ (((b >> 2) & 3) << 4))]);
    *reinterpret_cast<float4*>(
        out + ((size_t)b * (HH * WW) + hw) * COUT + co4q) = v;
  }
}

extern "C" void kernel_launch(void* const* d_in, const int* in_sizes, int n_in,
                              void* d_out, int out_size, void* d_ws,
                              size_t ws_size, hipStream_t stream) {
  const float* in = (const float*)d_in[0];
  const float* ker = (const float*)d_in[1];
  const float* bias = (const float*)d_in[2];
  float* out = (float*)d_out;
  (void)in_sizes; (void)n_in; (void)out_size; (void)d_ws; (void)ws_size;
  LocalConv_kernel<<<dim3(HH * WW), dim3(256), 0, stream>>>(in, ker, bias, out);
}